// Round 1
// 789.765 us; speedup vs baseline: 1.0013x; 1.0013x over previous
//
#include <hip/hip_runtime.h>
#include <math.h>

constexpr int B = 1024, C = 256, DF = 512, DT = 512, HID = 32;

// ---------------- Kernel 1: qtil[b,f] = sum_t Q[b,t] * Wk_w[t,f]  (fp32) ----------------
// NOTE: qtil is staged in d_out (out0), which is exactly B*DT*4 = 2 MB = B*DF*4.
// main_kernel block b reads qtil row b from out0 BEFORE overwriting it (block-local,
// read-before-write), so d_ws is never touched -> avoid the 2 GiB workspace poison fill
// that dominates the timed region (2x ~335 us fillBufferAligned in rocprof).
__global__ __launch_bounds__(256) void qproj_kernel(const float* __restrict__ Q,
                                                    const float* __restrict__ Wk,
                                                    float* __restrict__ qtil) {
    __shared__ __align__(16) float qs[4][DT];
    const int tid = threadIdx.x;
    const int b0 = blockIdx.x * 4;
#pragma unroll
    for (int bb = 0; bb < 4; bb++) {
        qs[bb][tid]       = Q[(b0 + bb) * DT + tid];
        qs[bb][tid + 256] = Q[(b0 + bb) * DT + tid + 256];
    }
    __syncthreads();
    const int f0 = tid * 2;
    float acc0[4] = {0.f, 0.f, 0.f, 0.f};
    float acc1[4] = {0.f, 0.f, 0.f, 0.f};
    for (int t4 = 0; t4 < DT; t4 += 4) {
        float q[4][4];
#pragma unroll
        for (int bb = 0; bb < 4; bb++) {
            float4 qv = *(const float4*)&qs[bb][t4];
            q[bb][0] = qv.x; q[bb][1] = qv.y; q[bb][2] = qv.z; q[bb][3] = qv.w;
        }
#pragma unroll
        for (int k = 0; k < 4; k++) {
            float2 w = *(const float2*)(Wk + (size_t)(t4 + k) * DF + f0);
#pragma unroll
            for (int bb = 0; bb < 4; bb++) {
                acc0[bb] += q[bb][k] * w.x;
                acc1[bb] += q[bb][k] * w.y;
            }
        }
    }
#pragma unroll
    for (int bb = 0; bb < 4; bb++) {
        float2 o; o.x = acc0[bb]; o.y = acc1[bb];
        *(float2*)(qtil + (size_t)(b0 + bb) * DF + f0) = o;
    }
}

// ---------------- Kernel 2: one block per batch ----------------
__global__ __launch_bounds__(256) void main_kernel(
    const float* __restrict__ Q, const float* __restrict__ feat,
    const float* __restrict__ qtil,
    const float* __restrict__ Wv, const float* __restrict__ Wvb,
    const float* __restrict__ g1w, const float* __restrict__ g1b,
    const float* __restrict__ g2w, const float* __restrict__ g2b,
    float* __restrict__ out0, float* __restrict__ out1) {

    __shared__ __align__(16) float s_q[DF];       // qtil[b]
    __shared__ __align__(16) float s_Q[DT];       // Q[b] (gate MLP)
    __shared__ __align__(16) float s_part[4][DF]; // per-wave partial r
    __shared__ __align__(16) float s_r[DF];       // weighted feature sum
    __shared__ __align__(16) float s_out[DT];     // feat_read staging
    __shared__ float s_m[4], s_l[4], s_abs[4];
    __shared__ float s_hp[HID][8];
    __shared__ float s_h[HID];
    __shared__ float s_gate;

    const int tid  = threadIdx.x;
    const int lane = tid & 63;
    const int wv   = tid >> 6;   // 4 waves
    const int b    = blockIdx.x;

    // qtil row b lives in out0 row b; consume it fully into LDS before we later
    // overwrite that row at the end of this block.
    s_q[tid]       = qtil[b * DF + tid];
    s_q[tid + 256] = qtil[b * DF + tid + 256];
    s_Q[tid]       = Q[b * DT + tid];
    s_Q[tid + 256] = Q[b * DT + tid + 256];
    __syncthreads();

    float qreg[8];
    {
        float4 a0 = *(const float4*)&s_q[lane * 8];
        float4 a1 = *(const float4*)&s_q[lane * 8 + 4];
        qreg[0] = a0.x; qreg[1] = a0.y; qreg[2] = a0.z; qreg[3] = a0.w;
        qreg[4] = a1.x; qreg[5] = a1.y; qreg[6] = a1.z; qreg[7] = a1.w;
    }

    const float* fb = feat + (size_t)b * C * DF;
    float r[8] = {0.f, 0.f, 0.f, 0.f, 0.f, 0.f, 0.f, 0.f};
    float m = -INFINITY, l = 0.f, sabs = 0.f;
    const float rs = 0.044194173824159216f;  // 1/sqrt(512)

    // streaming pass: scores + online softmax + weighted feature sum + abs-sum
    // 2 channels per iteration for reduce-chain ILP
    for (int c = wv * 64; c < wv * 64 + 64; c += 2) {
        const float* row0 = fb + (size_t)c * DF + lane * 8;
        const float* row1 = row0 + DF;
        float4 x0a = *(const float4*)row0;
        float4 x0b = *(const float4*)(row0 + 4);
        float4 x1a = *(const float4*)row1;
        float4 x1b = *(const float4*)(row1 + 4);
        float v0[8] = {x0a.x, x0a.y, x0a.z, x0a.w, x0b.x, x0b.y, x0b.z, x0b.w};
        float v1[8] = {x1a.x, x1a.y, x1a.z, x1a.w, x1b.x, x1b.y, x1b.z, x1b.w};
        float dot0 = 0.f, dot1 = 0.f;
#pragma unroll
        for (int j = 0; j < 8; j++) {
            dot0 += v0[j] * qreg[j];
            dot1 += v1[j] * qreg[j];
            sabs += fabsf(v0[j]) + fabsf(v1[j]);
        }
#pragma unroll
        for (int off = 1; off < 64; off <<= 1) {
            dot0 += __shfl_xor(dot0, off, 64);
            dot1 += __shfl_xor(dot1, off, 64);
        }
        float s0 = dot0 * rs, s1 = dot1 * rs;
        float m2 = fmaxf(fmaxf(m, s0), s1);
        float a  = __expf(m - m2);
        float p0 = __expf(s0 - m2);
        float p1 = __expf(s1 - m2);
        l = l * a + p0 + p1;
#pragma unroll
        for (int j = 0; j < 8; j++) r[j] = r[j] * a + p0 * v0[j] + p1 * v1[j];
        m = m2;
    }
#pragma unroll
    for (int off = 1; off < 64; off <<= 1) sabs += __shfl_xor(sabs, off, 64);
    if (lane == 0) { s_m[wv] = m; s_l[wv] = l; s_abs[wv] = sabs; }
    __syncthreads();

    float M = fmaxf(fmaxf(s_m[0], s_m[1]), fmaxf(s_m[2], s_m[3]));
    float L = s_l[0] * __expf(s_m[0] - M) + s_l[1] * __expf(s_m[1] - M) +
              s_l[2] * __expf(s_m[2] - M) + s_l[3] * __expf(s_m[3] - M);
    float msc = __expf(m - M);
#pragma unroll
    for (int j = 0; j < 8; j++) s_part[wv][lane * 8 + j] = r[j] * msc;
    float fscale = (s_abs[0] + s_abs[1] + s_abs[2] + s_abs[3]) * (1.0f / (float)(C * DF));
    __syncthreads();

    float invL = 1.0f / L;
#pragma unroll
    for (int k = 0; k < 2; k++) {
        int f = tid + 256 * k;
        s_r[f] = (s_part[0][f] + s_part[1][f] + s_part[2][f] + s_part[3][f]) * invL;
    }

    // gate MLP partials: 8 threads per hidden unit
    {
        int i = tid >> 3, g = tid & 7;
        const float* row = g1w + (size_t)i * (DT + 1);
        float part = 0.f;
        for (int t = g * 64; t < g * 64 + 64; ++t) part += row[t] * s_Q[t];
        if (g == 0) part += row[DT] * fscale;
        s_hp[i][g] = part;
    }
    __syncthreads();
    if (tid < HID) {
        float x = g1b[tid];
#pragma unroll
        for (int g = 0; g < 8; ++g) x += s_hp[tid][g];
        s_h[tid] = 0.5f * x * (1.0f + erff(x * 0.70710678118654752f));  // exact gelu
    }
    __syncthreads();
    if (tid == 0) {
        float z = g2b[0];
        for (int i = 0; i < HID; ++i) z += s_h[i] * g2w[i];
        float gate = 1.0f / (1.0f + __expf(-z));
        s_gate = gate;
        out1[b] = gate;
    }
    __syncthreads();

    // feat_read = Wv_w @ r + Wv_b ; out0 = gate * feat_read
    float gate = s_gate;
    float rr[8];
    {
        float4 a0 = *(const float4*)&s_r[lane * 8];
        float4 a1 = *(const float4*)&s_r[lane * 8 + 4];
        rr[0] = a0.x; rr[1] = a0.y; rr[2] = a0.z; rr[3] = a0.w;
        rr[4] = a1.x; rr[5] = a1.y; rr[6] = a1.z; rr[7] = a1.w;
    }
    for (int t = wv * 128; t < wv * 128 + 128; t += 2) {
        const float* w0p = Wv + (size_t)t * DF + lane * 8;
        const float* w1p = w0p + DF;
        float4 w0a = *(const float4*)w0p;
        float4 w0b = *(const float4*)(w0p + 4);
        float4 w1a = *(const float4*)w1p;
        float4 w1b = *(const float4*)(w1p + 4);
        float dot0 = w0a.x * rr[0] + w0a.y * rr[1] + w0a.z * rr[2] + w0a.w * rr[3]
                   + w0b.x * rr[4] + w0b.y * rr[5] + w0b.z * rr[6] + w0b.w * rr[7];
        float dot1 = w1a.x * rr[0] + w1a.y * rr[1] + w1a.z * rr[2] + w1a.w * rr[3]
                   + w1b.x * rr[4] + w1b.y * rr[5] + w1b.z * rr[6] + w1b.w * rr[7];
#pragma unroll
        for (int off = 1; off < 64; off <<= 1) {
            dot0 += __shfl_xor(dot0, off, 64);
            dot1 += __shfl_xor(dot1, off, 64);
        }
        if (lane == 0) {
            s_out[t]     = gate * (dot0 + Wvb[t]);
            s_out[t + 1] = gate * (dot1 + Wvb[t + 1]);
        }
    }
    __syncthreads();
    float2 o;
    o.x = s_out[2 * tid];
    o.y = s_out[2 * tid + 1];
    *(float2*)(out0 + (size_t)b * DT + 2 * tid) = o;
}

extern "C" void kernel_launch(void* const* d_in, const int* in_sizes, int n_in,
                              void* d_out, int out_size, void* d_ws, size_t ws_size,
                              hipStream_t stream) {
    const float* Q    = (const float*)d_in[0];
    const float* feat = (const float*)d_in[1];
    const float* Wk   = (const float*)d_in[2];
    // d_in[3] = Wk_b: constant across channels -> cancels in softmax (and is zeros), unused.
    const float* Wv   = (const float*)d_in[4];
    const float* Wvb  = (const float*)d_in[5];
    const float* g1w  = (const float*)d_in[6];
    const float* g1b  = (const float*)d_in[7];
    const float* g2w  = (const float*)d_in[8];
    const float* g2b  = (const float*)d_in[9];
    float* out0 = (float*)d_out;
    float* out1 = out0 + (size_t)B * DT;
    // qtil scratch lives in out0 (exactly B*DF*4 = 2 MB = out0 size).
    // d_ws is deliberately untouched (2 GiB poison-fill avoidance).
    float* qtil = out0;
    (void)d_ws; (void)ws_size;

    hipLaunchKernelGGL(qproj_kernel, dim3(B / 4), dim3(256), 0, stream, Q, Wk, qtil);
    hipLaunchKernelGGL(main_kernel, dim3(B), dim3(256), 0, stream,
                       Q, feat, qtil, Wv, Wvb, g1w, g1b, g2w, g2b, out0, out1);
}